// Round 5
// baseline (356.759 us; speedup 1.0000x reference)
//
#include <hip/hip_runtime.h>
#include <hip/hip_bf16.h>

#define BS     4
#define NQ     10000
#define NV     13294
#define EMBED  256
#define HEADS  8
#define LEVELS 4
#define POINTS 4
#define DH     32

typedef __attribute__((ext_vector_type(8))) short short8;
typedef __attribute__((ext_vector_type(4))) float floatx4;

static __device__ __forceinline__ unsigned short f2b(float f) {
    __hip_bfloat16 h = __float2bfloat16(f);   // RNE
    return *(unsigned short*)&h;
}
static __device__ __forceinline__ float b2f(unsigned short u) {
    return __uint_as_float(((unsigned int)u) << 16);
}
static __device__ __forceinline__ unsigned int pk_bf16(float x, float y) {
    __hip_bfloat162 h = __float22bfloat162_rn(make_float2(x, y));  // v_cvt_pk_bf16_f32
    unsigned int u; __builtin_memcpy(&u, &h, 4); return u;
}

// ---------------------------------------------------------------------------
// Weight prep: transpose+cast to bf16 [N][K], concat (Woff|Ww) and (boff|bw).
// ---------------------------------------------------------------------------
__global__ __launch_bounds__(256) void prep_weights(
    const float* __restrict__ Wv,  const float* __restrict__ Woff,
    const float* __restrict__ boff,const float* __restrict__ Ww,
    const float* __restrict__ bw,  const float* __restrict__ Wo,
    unsigned short* __restrict__ Wvt, unsigned short* __restrict__ Wcatt,
    unsigned short* __restrict__ Wot, float* __restrict__ bcat)
{
    const int n = blockIdx.x;
    const int k = threadIdx.x;   // 0..255
    if (n < 256) {
        Wvt[n * 256 + k] = f2b(Wv[k * 256 + n]);
    } else if (n < 512) {
        Wcatt[(n - 256) * 256 + k] = f2b(Woff[k * 256 + (n - 256)]);
    } else if (n < 640) {
        Wcatt[(n - 256) * 256 + k] = f2b(Ww[k * 128 + (n - 512)]);
    } else {
        Wot[(n - 640) * 256 + k] = f2b(Wo[k * 256 + (n - 640)]);
    }
    if (n == 0) {
        for (int j = k; j < 384; j += 256)
            bcat[j] = (j < 256) ? boff[j] : bw[j - 256];
    }
}

// ---------------------------------------------------------------------------
// LDS-free bf16 MFMA GEMM body: C[M x N] = A[M x 256] @ Bt^T + bias.
// Bt is [N][256] bf16. A-fragment (lane lr = m-row, 8 contiguous k) and
// B-fragment (lane lr = n-col, 8 contiguous k) are direct global 16 B loads
// -> zero LDS, zero barriers. Weights are L2-resident (every block re-reads).
// 256 threads = 4 waves in 2x2; block tile 128x128, wave tile 64x64.
// MODE 0: bf16 out; 2: fp32 out + residual. AF32: A is fp32 (convert inline).
// ---------------------------------------------------------------------------
template<int MODE, bool AF32>
static __device__ __forceinline__ void gemm_direct(
    const void* __restrict__ Aptr, int M,
    const unsigned short* __restrict__ Bt,
    const float* __restrict__ bias,
    void* __restrict__ Cv, int ldc,
    const float* __restrict__ residual,
    int mb, int nb)
{
    const int t    = threadIdx.x;
    const int lane = t & 63;
    const int wv   = t >> 6;
    const int wm   = mb * 128 + (wv & 1) * 64;
    const int wn   = nb * 128 + (wv >> 1) * 64;
    const int lr   = lane & 15;
    const int lk   = (lane >> 4) * 8;

    floatx4 acc[4][4] = {};

    int arow[4];
    #pragma unroll
    for (int mt = 0; mt < 4; ++mt)
        arow[mt] = min(wm + mt * 16 + lr, M - 1);   // clamp: OOB rows read row M-1, writes guarded

    #pragma unroll 2
    for (int k0 = 0; k0 < 256; k0 += 32) {
        short8 bf[4];
        #pragma unroll
        for (int nt = 0; nt < 4; ++nt)
            bf[nt] = *(const short8*)&Bt[(size_t)(wn + nt * 16 + lr) * 256 + k0 + lk];

        short8 af[4];
        #pragma unroll
        for (int mt = 0; mt < 4; ++mt) {
            if (AF32) {
                const float4* s = (const float4*)((const float*)Aptr + (size_t)arow[mt] * 256 + k0 + lk);
                const float4 f0 = s[0], f1 = s[1];
                union { short8 v; unsigned int u[4]; } cv;
                cv.u[0] = pk_bf16(f0.x, f0.y);
                cv.u[1] = pk_bf16(f0.z, f0.w);
                cv.u[2] = pk_bf16(f1.x, f1.y);
                cv.u[3] = pk_bf16(f1.z, f1.w);
                af[mt] = cv.v;
            } else {
                af[mt] = *(const short8*)&((const unsigned short*)Aptr)[(size_t)arow[mt] * 256 + k0 + lk];
            }
        }

        #pragma unroll
        for (int mt = 0; mt < 4; ++mt) {
            #pragma unroll
            for (int nt = 0; nt < 4; ++nt)
                acc[mt][nt] = __builtin_amdgcn_mfma_f32_16x16x32_bf16(af[mt], bf[nt], acc[mt][nt], 0, 0, 0);
        }
    }

    // epilogue: C/D layout col = lane&15, row = (lane>>4)*4 + reg
    const int rbase = wm + (lane >> 4) * 4;
    #pragma unroll
    for (int nt = 0; nt < 4; ++nt) {
        const int col = wn + nt * 16 + lr;
        const float bb = bias[col];
        #pragma unroll
        for (int mt = 0; mt < 4; ++mt) {
            #pragma unroll
            for (int r = 0; r < 4; ++r) {
                const int row = rbase + mt * 16 + r;
                if (row < M) {
                    float val = acc[mt][nt][r] + bb;
                    if (MODE == 2) val += residual[(size_t)row * ldc + col];
                    if (MODE == 0)
                        ((unsigned short*)Cv)[(size_t)row * ldc + col] = f2b(val);
                    else
                        ((float*)Cv)[(size_t)row * ldc + col] = val;
                }
            }
        }
    }
}

// Fused GEMM-V + GEMM-proj (independent, one dispatch).
// blocks [0, 832): v = value @ Wv + bv          (416 m-blocks x 2 n-blocks)
// blocks [832,1771): proj = query @ Wcat + bcat (313 m-blocks x 3 n-blocks)
__global__ __launch_bounds__(256) void gemm_fused12(
    const float* __restrict__ value, const float* __restrict__ query,
    const unsigned short* __restrict__ Wvt, const unsigned short* __restrict__ Wcatt,
    const float* __restrict__ bv, const float* __restrict__ bcat,
    unsigned short* __restrict__ vout, unsigned short* __restrict__ projout)
{
    const unsigned int bid = blockIdx.x;
    if (bid < 832u) {
        gemm_direct<0, true>(value, BS * NV, Wvt, bv, vout, 256, nullptr,
                             (int)(bid >> 1), (int)(bid & 1));
    } else {
        const unsigned int b2 = bid - 832u;
        gemm_direct<0, true>(query, BS * NQ, Wcatt, bcat, projout, 384, nullptr,
                             (int)(b2 / 3u), (int)(b2 % 3u));
    }
}

// out = msda @ Wo + bo + query  (fp32 out)
__global__ __launch_bounds__(256) void gemm_out(
    const unsigned short* __restrict__ msda, const unsigned short* __restrict__ Wot,
    const float* __restrict__ bo, float* __restrict__ out,
    const float* __restrict__ query)
{
    gemm_direct<2, false>(msda, BS * NQ, Wot, bo, out, 256, query,
                          (int)blockIdx.x, (int)blockIdx.y);
}

// ---------------------------------------------------------------------------
// Fused softmax + bilinear sampling, two-phase (proj bf16).
// ---------------------------------------------------------------------------
__global__ __launch_bounds__(256) void msda_sample(
    const unsigned short* __restrict__ v,
    const unsigned short* __restrict__ proj,
    const float* __restrict__ rp,
    unsigned short* __restrict__ out)
{
    __shared__ __align__(16) unsigned int taps[4 * 1056];  // 4 waves * 8 heads * 528 B

    const int wave = threadIdx.x >> 6;
    const int lane = threadIdx.x & 63;
    const int q = blockIdx.x * 4 + wave;
    const int b = blockIdx.y;
    const int rowq = b * NQ + q;
    const unsigned short* prow = proj + (size_t)rowq * 384;

    // ---- phase A: lane = h*8+i owns combos c = 2i, 2i+1 ----
    const int hA = lane >> 3;
    const int li = lane & 7;
    const int c0 = li * 2;

    const ushort2 lgu = *(const ushort2*)&prow[256 + hA * 16 + c0];
    const float lgx = b2f(lgu.x), lgy = b2f(lgu.y);
    float mx = fmaxf(lgx, lgy);
    mx = fmaxf(mx, __shfl_xor(mx, 1));
    mx = fmaxf(mx, __shfl_xor(mx, 2));
    mx = fmaxf(mx, __shfl_xor(mx, 4));
    const float e0 = __expf(lgx - mx);
    const float e1 = __expf(lgy - mx);
    float ssum = e0 + e1;
    ssum += __shfl_xor(ssum, 1);
    ssum += __shfl_xor(ssum, 2);
    ssum += __shfl_xor(ssum, 4);
    const float inv = 1.0f / ssum;

    const int l = c0 >> 2;   // both combos share the level
    const int Wl = (l == 0) ? 100 : (l == 1) ? 50 : (l == 2) ? 25 : 13;
    const int st = (l == 0) ? 0 : (l == 1) ? 10000 : (l == 2) ? 12500 : 13125;
    const int Hl = Wl;
    const float fW = (float)Wl, fH = (float)Hl;

    const float2 rxy = *(const float2*)&rp[((size_t)rowq * 4 + l) * 2];

    unsigned int* tbase = taps + wave * 1056 + hA * 132;

    #pragma unroll
    for (int cc = 0; cc < 2; ++cc) {
        const int c = c0 + cc;
        const ushort2 oxyu = *(const ushort2*)&prow[hA * 32 + c * 2];
        const float ox = b2f(oxyu.x), oy = b2f(oxyu.y);
        const float aww = (cc ? e1 : e0) * inv;
        const float x = fmaf(rxy.x, fW, ox) - 0.5f;
        const float y = fmaf(rxy.y, fH, oy) - 0.5f;
        const float x0f = floorf(x), y0f = floorf(y);
        const float fx = x - x0f, fy = y - y0f;
        const int ix = (int)x0f, iy = (int)y0f;
        const float wxv[2] = {1.f - fx, fx};
        const float wyv[2] = {1.f - fy, fy};

        uint4 ent[2];
        #pragma unroll
        for (int tp = 0; tp < 4; ++tp) {
            const int dy = tp >> 1, dx = tp & 1;
            const int xi = ix + dx, yi = iy + dy;
            const bool ok = (xi >= 0) && (xi < Wl) && (yi >= 0) && (yi < Hl);
            const int cx = min(max(xi, 0), Wl - 1);
            const int cy = min(max(yi, 0), Hl - 1);
            const unsigned int off = (unsigned int)(st + cy * Wl + cx) * 512u + (unsigned int)hA * 64u;
            const float w = ok ? wyv[dy] * wxv[dx] * aww : 0.f;
            ((unsigned int*)&ent[tp >> 1])[(tp & 1) * 2 + 0] = off;
            ((unsigned int*)&ent[tp >> 1])[(tp & 1) * 2 + 1] = __float_as_uint(w);
        }
        *(uint4*)&tbase[(c * 4 + 0) * 2] = ent[0];
        *(uint4*)&tbase[(c * 4 + 2) * 2] = ent[1];
    }

    __syncthreads();

    // ---- phase B: lane = h*8+i owns dims i*4..i*4+3 ----
    const int h = lane >> 3;
    const unsigned int lane_off = (unsigned int)(lane & 7) * 8u;
    const char* vbase = (const char*)v + (size_t)b * NV * 512;   // wave-uniform
    const uint4* tp4 = (const uint4*)(taps + wave * 1056 + h * 132);

    float a0 = 0.f, a1 = 0.f, a2 = 0.f, a3 = 0.f;
    #pragma unroll 8
    for (int j = 0; j < 32; ++j) {
        const uint4 ee = tp4[j];
        const uint2 g0 = *(const uint2*)(vbase + (ee.x + lane_off));
        const uint2 g1 = *(const uint2*)(vbase + (ee.z + lane_off));
        const float w0 = __uint_as_float(ee.y);
        const float w1 = __uint_as_float(ee.w);
        a0 = fmaf(w0, __uint_as_float(g0.x << 16), a0);
        a1 = fmaf(w0, __uint_as_float(g0.x & 0xFFFF0000u), a1);
        a2 = fmaf(w0, __uint_as_float(g0.y << 16), a2);
        a3 = fmaf(w0, __uint_as_float(g0.y & 0xFFFF0000u), a3);
        a0 = fmaf(w1, __uint_as_float(g1.x << 16), a0);
        a1 = fmaf(w1, __uint_as_float(g1.x & 0xFFFF0000u), a1);
        a2 = fmaf(w1, __uint_as_float(g1.y << 16), a2);
        a3 = fmaf(w1, __uint_as_float(g1.y & 0xFFFF0000u), a3);
    }

    ushort4 o;
    o.x = f2b(a0); o.y = f2b(a1); o.z = f2b(a2); o.w = f2b(a3);
    *(ushort4*)&out[(size_t)rowq * 256 + h * 32 + (lane & 7) * 4] = o;
}

// ---------------------------------------------------------------------------
// kernel_launch
// ---------------------------------------------------------------------------
extern "C" void kernel_launch(void* const* d_in, const int* in_sizes, int n_in,
                              void* d_out, int out_size, void* d_ws, size_t ws_size,
                              hipStream_t stream) {
    const float* query = (const float*)d_in[0];
    const float* value = (const float*)d_in[1];
    const float* rp    = (const float*)d_in[2];
    const float* Wv    = (const float*)d_in[4];
    const float* bv    = (const float*)d_in[5];
    const float* Woff  = (const float*)d_in[6];
    const float* boff  = (const float*)d_in[7];
    const float* Ww    = (const float*)d_in[8];
    const float* bw    = (const float*)d_in[9];
    const float* Wo    = (const float*)d_in[10];
    const float* bo    = (const float*)d_in[11];
    float* out = (float*)d_out;

    const int Mq = BS * NQ;   // 40000
    const int Mv = BS * NV;   // 53176

    char* ws = (char*)d_ws;
    const size_t SZ_MSDA = (size_t)Mq * 256 * 2;
    const size_t SZ_V    = (size_t)Mv * 256 * 2;
    const size_t SZ_PROJ = (size_t)Mq * 384 * 2;
    unsigned short* msda  = (unsigned short*)(ws);
    unsigned short* v_bf  = (unsigned short*)(ws + SZ_MSDA);
    unsigned short* proj  = (unsigned short*)(ws + SZ_MSDA + SZ_V);
    char* wp = ws + SZ_MSDA + SZ_V + SZ_PROJ;
    unsigned short* Wvt   = (unsigned short*)(wp);
    unsigned short* Wcatt = (unsigned short*)(wp + 256 * 256 * 2);
    unsigned short* Wot   = (unsigned short*)(wp + 256 * 256 * 2 + 384 * 256 * 2);
    float*          bcat  = (float*)(wp + 256 * 256 * 2 + 384 * 256 * 2 + 256 * 256 * 2);

    prep_weights<<<896, 256, 0, stream>>>(Wv, Woff, boff, Ww, bw, Wo, Wvt, Wcatt, Wot, bcat);

    // v = value @ Wv + bv (bf16) AND proj = query @ [Woff|Ww] + bias (bf16)
    gemm_fused12<<<832 + 939, 256, 0, stream>>>(
        value, query, Wvt, Wcatt, bv, bcat, v_bf, proj);

    // softmax + sampling -> msda (bf16)
    msda_sample<<<dim3(NQ / 4, BS), 256, 0, stream>>>(v_bf, proj, rp, msda);

    // out = msda @ Wo + bo + query
    gemm_out<<<dim3((Mq + 127) / 128, 2), 256, 0, stream>>>(msda, Wot, bo, out, query);
}